// Round 8
// baseline (247.661 us; speedup 1.0000x reference)
//
#include <hip/hip_runtime.h>
#include <hip/hip_bf16.h>
#include <cmath>

// Problem constants
#define BB 2
#define TT 2048
#define CC 1024
#define HH 16
#define DD 64
#define ROWS (BB*TT)          // 4096
#define N1 (3*CC)             // 3072
#define EPS 1e-6f

using short8 = __attribute__((ext_vector_type(8))) short;
using f32x4  = __attribute__((ext_vector_type(4))) float;

__device__ __forceinline__ void gl_lds16(const __hip_bfloat16* g, unsigned short* l) {
    __builtin_amdgcn_global_load_lds(
        (const __attribute__((address_space(1))) unsigned int*)(g),
        (__attribute__((address_space(3))) unsigned int*)(l), 16, 0, 0);
}

__device__ __forceinline__ unsigned int bf16pair(float a, float b) {
    __hip_bfloat16 ha = (__hip_bfloat16)a, hb = (__hip_bfloat16)b;  // RNE
    unsigned short ua = *(unsigned short*)&ha, ub = *(unsigned short*)&hb;
    return (unsigned int)ua | ((unsigned int)ub << 16);
}

__device__ __forceinline__ float bf2f(unsigned short u) {
    unsigned int v = (unsigned int)u << 16;
    return *(float*)&v;
}

// ------------------------------- rope table + wsq zero-init (folded memsets)
__global__ void rope_init(float* __restrict__ rope,
                          float* __restrict__ wsqa, float* __restrict__ wsqp) {
    int idx = blockIdx.x * 256 + threadIdx.x;      // 0 .. 65535
    if (idx < N1) wsqa[idx] = 0.f;
    if (idx < CC) wsqp[idx] = 0.f;
    if (idx >= TT * 32) return;
    int t = idx >> 5, i = idx & 31;
    double freq = pow(10000.0, -(double)i / 32.0);
    float ang = (float)t * (float)freq;
    rope[idx * 2 + 0] = cosf(ang);
    rope[idx * 2 + 1] = sinf(ang);
}

// --------------------- row sum-of-squares + bf16 cast (+ osq zero-init)
__global__ void rowsq_cast(const float* __restrict__ X, float* __restrict__ xsq,
                           __hip_bfloat16* __restrict__ Xb, float* __restrict__ osq) {
    int row = blockIdx.x;
    int t = threadIdx.x;
    const float* xr = X + (size_t)row * CC;
    __hip_bfloat16* br = Xb + (size_t)row * CC;
    float p = 0.f;
#pragma unroll
    for (int i = 0; i < 4; ++i) {
        float v = xr[t + i * 256];
        p += v * v;
        br[t + i * 256] = (__hip_bfloat16)v;
    }
    __shared__ float s[256];
    s[t] = p;
    __syncthreads();
    for (int off = 128; off > 0; off >>= 1) {
        if (t < off) s[t] += s[t + off];
        __syncthreads();
    }
    if (t == 0) { xsq[row] = s[0]; osq[row] = 0.f; }
}

// --------------------- transpose W (K x N fp32) -> Wt (N x K bf16) + col sq
__global__ void transpose_colsq(const float* __restrict__ W,
                                __hip_bfloat16* __restrict__ Wt,
                                float* __restrict__ wsq, int K, int N) {
    __shared__ unsigned short tile[64][65];
    int n0 = blockIdx.x * 64, k0 = blockIdx.y * 64;
    int c = threadIdx.x & 63, rg = threadIdx.x >> 6;
    float part = 0.f;
#pragma unroll
    for (int rr = 0; rr < 16; ++rr) {
        int r = rg + rr * 4;
        float f = W[(size_t)(k0 + r) * N + n0 + c];
        __hip_bfloat16 h = (__hip_bfloat16)f;
        tile[r][c] = *(unsigned short*)&h;
        part += f * f;
    }
    atomicAdd(&wsq[n0 + c], part);
    __syncthreads();
#pragma unroll
    for (int rr = 0; rr < 16; ++rr) {
        int r = rg + rr * 4;
        unsigned short u = tile[c][r];
        Wt[(size_t)(n0 + r) * K + k0 + c] = *(__hip_bfloat16*)&u;
    }
}

// ----------------- MFMA bf16 GEMM, BK=64 (half-split LDS), yat epilogue
template<int TM, int TN, typename OutT>
__global__ __launch_bounds__(256) void yat_gemm_bk64(
    const __hip_bfloat16* __restrict__ A,
    const __hip_bfloat16* __restrict__ Bt,
    const float* __restrict__ xsq, const float* __restrict__ wsq,
    const float* __restrict__ bias, OutT* __restrict__ C,
    int M, int N, int K, float scale) {
    constexpr int MT = TM / 32;
    constexpr int NT = TN / 32;
    constexpr int IA = TM / 64;       // 16-row staging chunks per wave (per half)
    constexpr int IB = TN / 64;
    __shared__ __align__(16) unsigned short As0[TM * 32];
    __shared__ __align__(16) unsigned short As1[TM * 32];
    __shared__ __align__(16) unsigned short Bs0[TN * 32];
    __shared__ __align__(16) unsigned short Bs1[TN * 32];
    int tid = threadIdx.x;
    int wave = tid >> 6, lane = tid & 63, quad = lane >> 4, l16 = lane & 15;
    int wr = wave >> 1, wc = wave & 1;
    int m0 = blockIdx.y * TM, n0 = blockIdx.x * TN;

    f32x4 acc[MT][NT];
#pragma unroll
    for (int mt = 0; mt < MT; ++mt)
#pragma unroll
        for (int nt = 0; nt < NT; ++nt) acc[mt][nt] = f32x4{0.f, 0.f, 0.f, 0.f};

    int srow = lane >> 2, soff = (lane & 3) << 3;
    for (int k0 = 0; k0 < K; k0 += 64) {
        __syncthreads();
#pragma unroll
        for (int i = 0; i < IA; ++i) {
            int rowc = (wave * IA + i) * 16;
            const __hip_bfloat16* ap = A + (size_t)(m0 + rowc + srow) * K + k0 + soff;
            gl_lds16(ap,      As0 + rowc * 32);
            gl_lds16(ap + 32, As1 + rowc * 32);
        }
#pragma unroll
        for (int i = 0; i < IB; ++i) {
            int rowc = (wave * IB + i) * 16;
            const __hip_bfloat16* bp = Bt + (size_t)(n0 + rowc + srow) * K + k0 + soff;
            gl_lds16(bp,      Bs0 + rowc * 32);
            gl_lds16(bp + 32, Bs1 + rowc * 32);
        }
        __syncthreads();
#pragma unroll
        for (int h = 0; h < 2; ++h) {
            const unsigned short* Ah = h ? As1 : As0;
            const unsigned short* Bh = h ? Bs1 : Bs0;
            short8 af[MT], bf[NT];
#pragma unroll
            for (int mt = 0; mt < MT; ++mt)
                af[mt] = *(const short8*)(Ah + (wr * (TM / 2) + mt * 16 + l16) * 32 + quad * 8);
#pragma unroll
            for (int nt = 0; nt < NT; ++nt)
                bf[nt] = *(const short8*)(Bh + (wc * (TN / 2) + nt * 16 + l16) * 32 + quad * 8);
#pragma unroll
            for (int mt = 0; mt < MT; ++mt)
#pragma unroll
                for (int nt = 0; nt < NT; ++nt)
                    acc[mt][nt] = __builtin_amdgcn_mfma_f32_16x16x32_bf16(af[mt], bf[nt], acc[mt][nt], 0, 0, 0);
        }
    }
    int mb = m0 + wr * (TM / 2) + quad * 4;
#pragma unroll
    for (int nt = 0; nt < NT; ++nt) {
        int col = n0 + wc * (TN / 2) + nt * 16 + l16;
        float wq = wsq[col];
        float bs = bias[col];
#pragma unroll
        for (int mt = 0; mt < MT; ++mt) {
#pragma unroll
            for (int r = 0; r < 4; ++r) {
                int row = mb + mt * 16 + r;
                float dot = acc[mt][nt][r];
                float dist = xsq[row] + wq - 2.f * dot + EPS;
                C[(size_t)row * N + col] = (OutT)(dot * dot / dist * scale + bs);
            }
        }
    }
}

// -------------------------- prep: bf16 qkv -> rope'd bf16 Q,K + V^T (bf16)
// Q pre-scale = 1/sqrt(64) * log2(e) so attention can use exp2 directly.
__global__ __launch_bounds__(256) void prep_qkv2(
    const unsigned short* __restrict__ qkvb, const float* __restrict__ rope,
    __hip_bfloat16* __restrict__ Qb, __hip_bfloat16* __restrict__ Kb,
    __hip_bfloat16* __restrict__ Vtb) {
    const float QSC = 0.125f * 1.44269504f;
    int t0 = blockIdx.x * 64;
    int h = blockIdx.y, b = blockIdx.z;
    int bh = b * HH + h;
    int tid = threadIdx.x;
    __shared__ unsigned short vt[64][72];
    int r = tid >> 2, g = tid & 3;
    int t = t0 + r;
    const unsigned short* base = qkvb + (size_t)(b * TT + t) * N1 + h * DD;
    const float* rp = rope + (size_t)t * 64;

    union U8 { uint4 v; unsigned short s[8]; };
    U8 qa, qb2, ka, kb2, va, vb2;
    qa.v  = *(const uint4*)(base + g * 16);
    qb2.v = *(const uint4*)(base + g * 16 + 8);
    ka.v  = *(const uint4*)(base + CC + g * 16);
    kb2.v = *(const uint4*)(base + CC + g * 16 + 8);
    va.v  = *(const uint4*)(base + 2 * CC + g * 16);
    vb2.v = *(const uint4*)(base + 2 * CC + g * 16 + 8);

    U8 qo0, qo1, ko0, ko1;
#pragma unroll
    for (int u = 0; u < 8; ++u) {
        int i = g * 8 + u;              // freq index for local pair u
        float cs = rp[2 * i], sn = rp[2 * i + 1];
        unsigned short uq0 = (u < 4) ? qa.s[2 * u] : qb2.s[2 * u - 8];
        unsigned short uq1 = (u < 4) ? qa.s[2 * u + 1] : qb2.s[2 * u - 7];
        unsigned short uk0 = (u < 4) ? ka.s[2 * u] : kb2.s[2 * u - 8];
        unsigned short uk1 = (u < 4) ? ka.s[2 * u + 1] : kb2.s[2 * u - 7];
        float q0 = bf2f(uq0), q1 = bf2f(uq1);
        float k0 = bf2f(uk0), k1 = bf2f(uk1);
        unsigned int qp = bf16pair((q0 * cs - q1 * sn) * QSC, (q1 * cs + q0 * sn) * QSC);
        unsigned int kp = bf16pair(k0 * cs - k1 * sn, k1 * cs + k0 * sn);
        if (u < 4) { ((unsigned int*)&qo0)[u] = qp; ((unsigned int*)&ko0)[u] = kp; }
        else       { ((unsigned int*)&qo1)[u - 4] = qp; ((unsigned int*)&ko1)[u - 4] = kp; }
    }
    __hip_bfloat16* qd = Qb + ((size_t)bh * TT + t) * DD + g * 16;
    __hip_bfloat16* kd = Kb + ((size_t)bh * TT + t) * DD + g * 16;
    *(uint4*)(qd) = qo0.v;  *(uint4*)(qd + 8) = qo1.v;
    *(uint4*)(kd) = ko0.v;  *(uint4*)(kd + 8) = ko1.v;

    *(uint4*)(&vt[r][g * 16]) = va.v;
    *(uint4*)(&vt[r][g * 16 + 8]) = vb2.v;
    __syncthreads();
    // coalesced V^T store: thread owns (d = tid>>3 [+32], t chunk of 8)
#pragma unroll
    for (int p = 0; p < 2; ++p) {
        int d = (tid >> 3) + p * 32;
        int tl = (tid & 7) * 8;
        U8 w;
#pragma unroll
        for (int j = 0; j < 8; ++j) w.s[j] = vt[tl + j][d];
        *(uint4*)(Vtb + ((size_t)bh * DD + d) * TT + t0 + tl) = w.v;
    }
}

// ------------------------------------ LDS-staged MFMA flash attention v2
// Block = 2 waves (128 thr), 64 q-rows; wave owns 32 rows as 2 strips of 16
// sharing each staged K/V tile (36 MFMA per wave per tile). Grid 1024
// (4 blocks/CU). S^T = K·Q^T, O^T = V^T·P^T; P strip wave-private.
__global__ __launch_bounds__(128) void attn_mfma7(
    const __hip_bfloat16* __restrict__ Qb, const __hip_bfloat16* __restrict__ Kb,
    const __hip_bfloat16* __restrict__ Vtb,
    __hip_bfloat16* __restrict__ out, float* __restrict__ osq) {
    int i = blockIdx.x;
    int xcd = i & 7;
    int r0 = i >> 3;                 // 0..127
    int bh = xcd + 8 * (r0 & 3);     // 4 bh per XCD (L2 locality)
    int rr = r0 >> 2;                // 0..31
    int v = rr & 7, s2 = rr >> 3;
    // balanced per-CU qblk sets {v, 15-v, 16+v, 31-v} (sum of tiles = 66)
    int qblk = (s2 == 0) ? v : (s2 == 1) ? (15 - v) : (s2 == 2) ? (16 + v) : (31 - v);
    int b = bh >> 4, h = bh & 15;
    int tid = threadIdx.x;
    int wave = tid >> 6, lane = tid & 63, quad = lane >> 4, l16 = lane & 15;

    __shared__ __align__(16) unsigned short Ks0[64 * 32], Ks1[64 * 32];  // keys x d-half
    __shared__ __align__(16) unsigned short Vs0[64 * 32], Vs1[64 * 32];  // d x key-half
    __shared__ __align__(16) unsigned short Ps[2][16 * 72];
    unsigned short* pp = &Ps[wave][0];

    const __hip_bfloat16* Qbase = Qb + (size_t)bh * TT * DD;
    const __hip_bfloat16* Kbase = Kb + (size_t)bh * TT * DD;
    const __hip_bfloat16* Vbase = Vtb + (size_t)bh * DD * TT;

    int qw = qblk * 64 + wave * 32;     // wave's first q row
    short8 qf[2][2];
#pragma unroll
    for (int s = 0; s < 2; ++s) {
        const __hip_bfloat16* qr = Qbase + (size_t)(qw + s * 16 + l16) * DD + quad * 8;
        qf[s][0] = *(const short8*)(qr);
        qf[s][1] = *(const short8*)(qr + 32);
    }
    short8 ones8;
#pragma unroll
    for (int u = 0; u < 8; ++u) ones8[u] = (short)0x3F80;   // bf16 1.0

    f32x4 acc_o[2][4];
#pragma unroll
    for (int s = 0; s < 2; ++s)
#pragma unroll
        for (int mt = 0; mt < 4; ++mt) acc_o[s][mt] = f32x4{0.f, 0.f, 0.f, 0.f};
    f32x4 acc_l[2] = {{0.f, 0.f, 0.f, 0.f}, {0.f, 0.f, 0.f, 0.f}};

    int srow = lane >> 2, soff = (lane & 3) << 3;

    for (int kt = 0; kt <= qblk; ++kt) {
        int k0 = kt * 64;
        __syncthreads();               // previous tile's LDS reads complete
#pragma unroll
        for (int j = 0; j < 2; ++j) {
            int row = wave * 32 + j * 16;      // wave stages 32 of the 64 rows
            const __hip_bfloat16* kp = Kbase + (size_t)(k0 + row + srow) * DD + soff;
            gl_lds16(kp,      Ks0 + row * 32);
            gl_lds16(kp + 32, Ks1 + row * 32);
            const __hip_bfloat16* vp = Vbase + (size_t)(row + srow) * TT + k0 + soff;
            gl_lds16(vp,      Vs0 + row * 32);
            gl_lds16(vp + 32, Vs1 + row * 32);
        }
        __syncthreads();               // staging visible to both waves
        bool diag = (kt == qblk);
#pragma unroll
        for (int s = 0; s < 2; ++s) {
            // S^T = K·Q^T: A = K rows (keys), B = Q rows
            f32x4 accs[4];
#pragma unroll
            for (int mt = 0; mt < 4; ++mt) {
                short8 kf0 = *(const short8*)(Ks0 + (mt * 16 + l16) * 32 + quad * 8);
                short8 kf1 = *(const short8*)(Ks1 + (mt * 16 + l16) * 32 + quad * 8);
                f32x4 z = {0.f, 0.f, 0.f, 0.f};
                z = __builtin_amdgcn_mfma_f32_16x16x32_bf16(kf0, qf[s][0], z, 0, 0, 0);
                accs[mt] = __builtin_amdgcn_mfma_f32_16x16x32_bf16(kf1, qf[s][1], z, 0, 0, 0);
            }
            int limit = diag ? (qw + s * 16 + l16) : 0x7FFFFFFF;
#pragma unroll
            for (int mt = 0; mt < 4; ++mt) {
                int keyb = k0 + mt * 16 + quad * 4;
                float p0 = exp2f(accs[mt][0]);
                float p1 = exp2f(accs[mt][1]);
                float p2 = exp2f(accs[mt][2]);
                float p3 = exp2f(accs[mt][3]);
                p0 = (keyb + 0 <= limit) ? p0 : 0.f;
                p1 = (keyb + 1 <= limit) ? p1 : 0.f;
                p2 = (keyb + 2 <= limit) ? p2 : 0.f;
                p3 = (keyb + 3 <= limit) ? p3 : 0.f;
                uint2 w2;
                w2.x = bf16pair(p0, p1);
                w2.y = bf16pair(p2, p3);
                *(uint2*)(pp + l16 * 72 + mt * 16 + quad * 4) = w2;   // P[q=l16][key]
            }
            short8 pf0 = *(const short8*)(pp + l16 * 72 + quad * 8);
            short8 pf1 = *(const short8*)(pp + l16 * 72 + 32 + quad * 8);
            // O^T += V^T·P^T: A = V^T rows (d), halves by key
#pragma unroll
            for (int mt = 0; mt < 4; ++mt) {
                short8 vf0 = *(const short8*)(Vs0 + (mt * 16 + l16) * 32 + quad * 8);
                short8 vf1 = *(const short8*)(Vs1 + (mt * 16 + l16) * 32 + quad * 8);
                acc_o[s][mt] = __builtin_amdgcn_mfma_f32_16x16x32_bf16(vf0, pf0, acc_o[s][mt], 0, 0, 0);
                acc_o[s][mt] = __builtin_amdgcn_mfma_f32_16x16x32_bf16(vf1, pf1, acc_o[s][mt], 0, 0, 0);
            }
            acc_l[s] = __builtin_amdgcn_mfma_f32_16x16x32_bf16(ones8, pf0, acc_l[s], 0, 0, 0);
            acc_l[s] = __builtin_amdgcn_mfma_f32_16x16x32_bf16(ones8, pf1, acc_l[s], 0, 0, 0);
        }
    }
    // epilogue per strip: normalize, osq, transpose via wave-private strip, store
#pragma unroll
    for (int s = 0; s < 2; ++s) {
        float inv = 1.f / acc_l[s][0];
        int qs = qw + s * 16;
        float part = 0.f;
#pragma unroll
        for (int mt = 0; mt < 4; ++mt) {
            float o0 = acc_o[s][mt][0] * inv;
            float o1 = acc_o[s][mt][1] * inv;
            float o2 = acc_o[s][mt][2] * inv;
            float o3 = acc_o[s][mt][3] * inv;
            part += o0 * o0 + o1 * o1 + o2 * o2 + o3 * o3;
            uint2 w2;
            w2.x = bf16pair(o0, o1);
            w2.y = bf16pair(o2, o3);
            // O[q = l16][d = mt*16 + quad*4 + ri]
            *(uint2*)(pp + l16 * 72 + mt * 16 + quad * 4) = w2;
        }
        part += __shfl_xor(part, 16, 64);
        part += __shfl_xor(part, 32, 64);
        if (quad == 0) atomicAdd(&osq[(size_t)b * TT + qs + l16], part);
        int rw = lane >> 2, cg = lane & 3;
        uint4 o0 = *(const uint4*)(pp + rw * 72 + cg * 16);
        uint4 o1 = *(const uint4*)(pp + rw * 72 + cg * 16 + 8);
        __hip_bfloat16* orow = out + (size_t)(b * TT + qs + rw) * CC + h * DD + cg * 16;
        *(uint4*)(orow) = o0;
        *(uint4*)(orow + 8) = o1;
    }
}

// ---------------------------------------------------------------- launcher
extern "C" void kernel_launch(void* const* d_in, const int* in_sizes, int n_in,
                              void* d_out, int out_size, void* d_ws, size_t ws_size,
                              hipStream_t stream) {
    const float* x      = (const float*)d_in[0];
    // d_in[1] = mask (causal tril) — implied analytically, unused
    const float* w_attn = (const float*)d_in[2];
    const float* b_attn = (const float*)d_in[3];
    const float* w_proj = (const float*)d_in[4];
    const float* b_proj = (const float*)d_in[5];
    float* out = (float*)d_out;

    char* ws = (char*)d_ws;
    __hip_bfloat16* qkvb = (__hip_bfloat16*)(ws + 0);         // 4096x3072 bf16
    __hip_bfloat16* xbf  = (__hip_bfloat16*)(ws + 25165824);  // 8 MB
    __hip_bfloat16* aout = (__hip_bfloat16*)(ws + 33554432);  // 8 MB
    __hip_bfloat16* watT = (__hip_bfloat16*)(ws + 41943040);  // 6 MB
    __hip_bfloat16* wpT  = (__hip_bfloat16*)(ws + 48234496);  // 2 MB
    float*          rope = (float*)(ws + 50331648);           // 512 KB
    float*          xsq  = (float*)(ws + 50855936);           // 16 KB
    float*          osq  = (float*)(ws + 50872320);           // 16 KB
    float*          wsqa = (float*)(ws + 50888704);           // 12 KB
    float*          wsqp = (float*)(ws + 50900992);           // 4 KB
    __hip_bfloat16* Qb   = (__hip_bfloat16*)(ws + 50905088);  // 8 MB
    __hip_bfloat16* Kb   = (__hip_bfloat16*)(ws + 59293696);  // 8 MB
    __hip_bfloat16* Vtb  = (__hip_bfloat16*)(ws + 67682304);  // 8 MB

    float scale1 = (float)(sqrt(3072.0) / log1p(3072.0));
    float scale2 = (float)(sqrt(1024.0) / log1p(1024.0));

    rope_init<<<256, 256, 0, stream>>>(rope, wsqa, wsqp);
    rowsq_cast<<<ROWS, 256, 0, stream>>>(x, xsq, xbf, osq);
    transpose_colsq<<<dim3(N1 / 64, CC / 64), 256, 0, stream>>>(w_attn, watT, wsqa, CC, N1);
    transpose_colsq<<<dim3(CC / 64, CC / 64), 256, 0, stream>>>(w_proj, wpT, wsqp, CC, CC);
    yat_gemm_bk64<128, 128, __hip_bfloat16><<<dim3(N1 / 128, ROWS / 128), 256, 0, stream>>>(
        xbf, watT, xsq, wsqa, b_attn, qkvb, ROWS, N1, CC, scale1);
    prep_qkv2<<<dim3(TT / 64, HH, BB), 256, 0, stream>>>(
        (const unsigned short*)qkvb, rope, Qb, Kb, Vtb);
    attn_mfma7<<<1024, 128, 0, stream>>>(Qb, Kb, Vtb, aout, osq);
    yat_gemm_bk64<128, 64, float><<<dim3(CC / 64, ROWS / 128), 256, 0, stream>>>(
        aout, wpT, osq, wsqp, b_proj, out, ROWS, CC, CC, scale2);
}

// Round 9
// 246.769 us; speedup vs baseline: 1.0036x; 1.0036x over previous
//
#include <hip/hip_runtime.h>
#include <hip/hip_bf16.h>
#include <cmath>

// Problem constants
#define BB 2
#define TT 2048
#define CC 1024
#define HH 16
#define DD 64
#define ROWS (BB*TT)          // 4096
#define N1 (3*CC)             // 3072
#define EPS 1e-6f

using short8 = __attribute__((ext_vector_type(8))) short;
using f32x4  = __attribute__((ext_vector_type(4))) float;

__device__ __forceinline__ void gl_lds16(const __hip_bfloat16* g, unsigned short* l) {
    __builtin_amdgcn_global_load_lds(
        (const __attribute__((address_space(1))) unsigned int*)(g),
        (__attribute__((address_space(3))) unsigned int*)(l), 16, 0, 0);
}

__device__ __forceinline__ unsigned int bf16pair(float a, float b) {
    __hip_bfloat16 ha = (__hip_bfloat16)a, hb = (__hip_bfloat16)b;  // RNE
    unsigned short ua = *(unsigned short*)&ha, ub = *(unsigned short*)&hb;
    return (unsigned int)ua | ((unsigned int)ub << 16);
}

// ---------------- fused: row sum-of-squares + bf16 cast + rope table + zeroes
__global__ void rope_rowsq(const float* __restrict__ X, float* __restrict__ xsq,
                           __hip_bfloat16* __restrict__ Xb, float* __restrict__ osq,
                           float* __restrict__ rope,
                           float* __restrict__ wsqa, float* __restrict__ wsqp) {
    int blk = blockIdx.x;
    int t = threadIdx.x;
    if (blk >= ROWS) {      // tail blocks: rope table + wsq/osq-independent inits
        int idx = (blk - ROWS) * 256 + t;
        if (idx < N1) wsqa[idx] = 0.f;
        if (idx < CC) wsqp[idx] = 0.f;
        if (idx < TT * 32) {
            int tt = idx >> 5, i = idx & 31;
            double freq = pow(10000.0, -(double)i / 32.0);
            float ang = (float)tt * (float)freq;
            rope[idx * 2 + 0] = cosf(ang);
            rope[idx * 2 + 1] = sinf(ang);
        }
        return;
    }
    int row = blk;
    const float* xr = X + (size_t)row * CC;
    __hip_bfloat16* br = Xb + (size_t)row * CC;
    float p = 0.f;
#pragma unroll
    for (int i = 0; i < 4; ++i) {
        float v = xr[t + i * 256];
        p += v * v;
        br[t + i * 256] = (__hip_bfloat16)v;
    }
    __shared__ float s[256];
    s[t] = p;
    __syncthreads();
    for (int off = 128; off > 0; off >>= 1) {
        if (t < off) s[t] += s[t + off];
        __syncthreads();
    }
    if (t == 0) { xsq[row] = s[0]; osq[row] = 0.f; }
}

// ---------- fused transpose of both weights: W (KxN fp32) -> Wt (NxK bf16) + colsq
__global__ void transpose2(const float* __restrict__ Wa, __hip_bfloat16* __restrict__ WaT,
                           float* __restrict__ wsqa,
                           const float* __restrict__ Wp, __hip_bfloat16* __restrict__ WpT,
                           float* __restrict__ wsqp) {
    const float* W; __hip_bfloat16* Wt; float* wsq; int N;
    if (blockIdx.z == 0) { W = Wa; Wt = WaT; wsq = wsqa; N = N1; }
    else { if (blockIdx.x >= 16) return; W = Wp; Wt = WpT; wsq = wsqp; N = CC; }
    const int K = CC;
    __shared__ unsigned short tile[64][65];
    int n0 = blockIdx.x * 64, k0 = blockIdx.y * 64;
    int c = threadIdx.x & 63, rg = threadIdx.x >> 6;
    float part = 0.f;
#pragma unroll
    for (int rr = 0; rr < 16; ++rr) {
        int r = rg + rr * 4;
        float f = W[(size_t)(k0 + r) * N + n0 + c];
        __hip_bfloat16 h = (__hip_bfloat16)f;
        tile[r][c] = *(unsigned short*)&h;
        part += f * f;
    }
    atomicAdd(&wsq[n0 + c], part);
    __syncthreads();
#pragma unroll
    for (int rr = 0; rr < 16; ++rr) {
        int r = rg + rr * 4;
        unsigned short u = tile[c][r];
        Wt[(size_t)(n0 + r) * K + k0 + c] = *(__hip_bfloat16*)&u;
    }
}

// --------- gemm1: x @ w_attn with yat epilogue + fused RoPE, writes Q/K/V
// 128x128 tile, BK=64. Q pre-scaled by 0.125*log2(e). Layouts:
// Qb/Kb [bh][t][d] (roped), Vb [bh][t][d] natural.
__global__ __launch_bounds__(256) void yat_gemm_qkv(
    const __hip_bfloat16* __restrict__ A,
    const __hip_bfloat16* __restrict__ Bt,
    const float* __restrict__ xsq, const float* __restrict__ wsq,
    const float* __restrict__ bias, const float* __restrict__ rope,
    __hip_bfloat16* __restrict__ Qb, __hip_bfloat16* __restrict__ Kb,
    __hip_bfloat16* __restrict__ Vb, float scale) {
    const int K = CC, N = N1;
    __shared__ __align__(16) unsigned short As0[128 * 32], As1[128 * 32];
    __shared__ __align__(16) unsigned short Bs0[128 * 32], Bs1[128 * 32];
    int tid = threadIdx.x;
    int wave = tid >> 6, lane = tid & 63, quad = lane >> 4, l16 = lane & 15;
    int wr = wave >> 1, wc = wave & 1;
    int m0 = blockIdx.y * 128, n0 = blockIdx.x * 128;

    f32x4 acc[4][4];
#pragma unroll
    for (int mt = 0; mt < 4; ++mt)
#pragma unroll
        for (int nt = 0; nt < 4; ++nt) acc[mt][nt] = f32x4{0.f, 0.f, 0.f, 0.f};

    int srow = lane >> 2, soff = (lane & 3) << 3;
    for (int k0 = 0; k0 < K; k0 += 64) {
        __syncthreads();
#pragma unroll
        for (int i = 0; i < 2; ++i) {
            int rowc = (wave * 2 + i) * 16;
            const __hip_bfloat16* ap = A + (size_t)(m0 + rowc + srow) * K + k0 + soff;
            gl_lds16(ap,      As0 + rowc * 32);
            gl_lds16(ap + 32, As1 + rowc * 32);
            const __hip_bfloat16* bp = Bt + (size_t)(n0 + rowc + srow) * K + k0 + soff;
            gl_lds16(bp,      Bs0 + rowc * 32);
            gl_lds16(bp + 32, Bs1 + rowc * 32);
        }
        __syncthreads();
#pragma unroll
        for (int h = 0; h < 2; ++h) {
            const unsigned short* Ah = h ? As1 : As0;
            const unsigned short* Bh = h ? Bs1 : Bs0;
            short8 af[4], bf[4];
#pragma unroll
            for (int mt = 0; mt < 4; ++mt)
                af[mt] = *(const short8*)(Ah + (wr * 64 + mt * 16 + l16) * 32 + quad * 8);
#pragma unroll
            for (int nt = 0; nt < 4; ++nt)
                bf[nt] = *(const short8*)(Bh + (wc * 64 + nt * 16 + l16) * 32 + quad * 8);
#pragma unroll
            for (int mt = 0; mt < 4; ++mt)
#pragma unroll
                for (int nt = 0; nt < 4; ++nt)
                    acc[mt][nt] = __builtin_amdgcn_mfma_f32_16x16x32_bf16(af[mt], bf[nt], acc[mt][nt], 0, 0, 0);
        }
    }
    // epilogue: yat + rope (q/k) / passthrough (v)
    const float QSC = 0.125f * 1.44269504f;
    int mb = m0 + wr * 64 + quad * 4;
    int cbase = n0 + wc * 64;
    int sec = n0 >> 10;                 // 0=q, 1=k, 2=v (128 | 1024)
    if (sec == 2) {
#pragma unroll
        for (int nt = 0; nt < 4; ++nt) {
            int col = cbase + nt * 16 + l16;
            float wq = wsq[col], bs = bias[col];
            int h = (col & 1023) >> 6, d = col & 63;
#pragma unroll
            for (int mt = 0; mt < 4; ++mt) {
#pragma unroll
                for (int r = 0; r < 4; ++r) {
                    int row = mb + mt * 16 + r;
                    float dot = acc[mt][nt][r];
                    float dist = xsq[row] + wq - 2.f * dot + EPS;
                    float y = dot * dot / dist * scale + bs;
                    int t = row & (TT - 1), bI = row >> 11;
                    Vb[(((size_t)bI * HH + h) * TT + t) * DD + d] = (__hip_bfloat16)y;
                }
            }
        }
    } else {
        __hip_bfloat16* dst = sec ? Kb : Qb;
        float sc = sec ? 1.f : QSC;
#pragma unroll
        for (int nt = 0; nt < 4; ++nt) {
            int col = cbase + nt * 16 + l16;
            float wq = wsq[col], bs = bias[col];
            int h = (col & 1023) >> 6, d = col & 63;
            int odd = l16 & 1;
#pragma unroll
            for (int mt = 0; mt < 4; ++mt) {
#pragma unroll
                for (int r = 0; r < 4; ++r) {
                    int row = mb + mt * 16 + r;
                    float dot = acc[mt][nt][r];
                    float dist = xsq[row] + wq - 2.f * dot + EPS;
                    float y = dot * dot / dist * scale + bs;
                    float yp = __shfl_xor(y, 1, 64);      // partner col^1
                    int t = row & (TT - 1), bI = row >> 11;
                    const float* rp = rope + (size_t)t * 64 + (d & 62);
                    float cs = rp[0] * sc, sn = rp[1] * sc;
                    float o = odd ? (y * cs + yp * sn) : (y * cs - yp * sn);
                    dst[(((size_t)bI * HH + h) * TT + t) * DD + d] = (__hip_bfloat16)o;
                }
            }
        }
    }
}

// --------------------------- V transpose: Vb [bh][t][d] -> Vtb [bh][d][t]
__global__ __launch_bounds__(256) void vtrans(const unsigned short* __restrict__ Vb,
                                              __hip_bfloat16* __restrict__ Vtb) {
    int bh = blockIdx.y, t0 = blockIdx.x * 64, tid = threadIdx.x;
    __shared__ unsigned short vt[64][72];
    int r = tid >> 2, g = (tid & 3) * 16;
    const unsigned short* src = Vb + ((size_t)bh * TT + t0 + r) * DD + g;
    *(uint4*)&vt[r][g]     = *(const uint4*)src;
    *(uint4*)&vt[r][g + 8] = *(const uint4*)(src + 8);
    __syncthreads();
    union U8 { uint4 v; unsigned short s[8]; };
#pragma unroll
    for (int p = 0; p < 2; ++p) {
        int d = (tid >> 3) + p * 32, tl = (tid & 7) * 8;
        U8 w;
#pragma unroll
        for (int j = 0; j < 8; ++j) w.s[j] = vt[tl + j][d];
        *(uint4*)(Vtb + ((size_t)bh * DD + d) * TT + t0 + tl) = w.v;
    }
}

// ------------------------------------ LDS-staged MFMA flash attention
// Block = 4 waves, 64 q-rows (16/wave). K/V tiles staged once per block via
// global_load_lds, shared by all 4 waves. S^T = K·Q^T, O^T = V^T·P^T;
// P strip wave-private (no barrier). Grid 1024 -> 4 blocks/CU, 16 waves/CU.
__global__ __launch_bounds__(256, 3) void attn_mfma6(
    const __hip_bfloat16* __restrict__ Qb, const __hip_bfloat16* __restrict__ Kb,
    const __hip_bfloat16* __restrict__ Vtb,
    __hip_bfloat16* __restrict__ out, float* __restrict__ osq) {
    int i = blockIdx.x;
    int xcd = i & 7;
    int r0 = i >> 3;                 // 0..127
    int bh = xcd + 8 * (r0 & 3);     // 4 bh per XCD (L2 locality)
    int rr = r0 >> 2;                // 0..31
    int v = rr & 7, s2 = rr >> 3;
    // balanced qblk sets {v, 15-v, 16+v, 31-v}
    int qblk = (s2 == 0) ? v : (s2 == 1) ? (15 - v) : (s2 == 2) ? (16 + v) : (31 - v);
    int b = bh >> 4, h = bh & 15;
    int tid = threadIdx.x;
    int wave = tid >> 6, lane = tid & 63, quad = lane >> 4, l16 = lane & 15;

    __shared__ __align__(16) unsigned short Ks[2][64 * 32];   // [d-half][key row][32]
    __shared__ __align__(16) unsigned short Vs[2][64 * 32];   // [key-half][d row][32]
    __shared__ __align__(16) unsigned short Ps[4][16 * 72];
    unsigned short* pp = &Ps[wave][0];

    const __hip_bfloat16* Qbase = Qb + (size_t)bh * TT * DD;
    const __hip_bfloat16* Kbase = Kb + (size_t)bh * TT * DD;
    const __hip_bfloat16* Vbase = Vtb + (size_t)bh * DD * TT;

    int qw = qblk * 64 + wave * 16;     // wave's first q row
    short8 qf0, qf1;
    {
        const __hip_bfloat16* qr = Qbase + (size_t)(qw + l16) * DD + quad * 8;
        qf0 = *(const short8*)(qr);
        qf1 = *(const short8*)(qr + 32);
    }
    short8 ones8;
#pragma unroll
    for (int u = 0; u < 8; ++u) ones8[u] = (short)0x3F80;   // bf16 1.0

    f32x4 acc_o[4];
#pragma unroll
    for (int mt = 0; mt < 4; ++mt) acc_o[mt] = f32x4{0.f, 0.f, 0.f, 0.f};
    f32x4 acc_l = {0.f, 0.f, 0.f, 0.f};

    // staging lane mapping: one inst = 16 rows x 32 shorts (1 KB)
    int srow = lane >> 2;              // 0..15
    int soff = (lane & 3) * 8;         // shorts within 32
    int q_g = qw + l16;

    for (int kt = 0; kt <= qblk; ++kt) {
        int k0 = kt * 64;
        __syncthreads();               // previous tile's LDS reads complete
        gl_lds16(Kbase + (size_t)(k0 + wave * 16 + srow) * DD + soff,      &Ks[0][wave * 512]);
        gl_lds16(Kbase + (size_t)(k0 + wave * 16 + srow) * DD + 32 + soff, &Ks[1][wave * 512]);
        gl_lds16(Vbase + (size_t)(wave * 16 + srow) * TT + k0 + soff,      &Vs[0][wave * 512]);
        gl_lds16(Vbase + (size_t)(wave * 16 + srow) * TT + k0 + 32 + soff, &Vs[1][wave * 512]);
        __syncthreads();               // staging visible to all waves

        // S^T = K·Q^T: A = K rows (keys), B = Q rows
        f32x4 accs[4];
#pragma unroll
        for (int mt = 0; mt < 4; ++mt) {
            short8 kf0 = *(const short8*)(&Ks[0][(mt * 16 + l16) * 32 + quad * 8]);
            short8 kf1 = *(const short8*)(&Ks[1][(mt * 16 + l16) * 32 + quad * 8]);
            f32x4 z = {0.f, 0.f, 0.f, 0.f};
            z = __builtin_amdgcn_mfma_f32_16x16x32_bf16(kf0, qf0, z, 0, 0, 0);
            accs[mt] = __builtin_amdgcn_mfma_f32_16x16x32_bf16(kf1, qf1, z, 0, 0, 0);
        }
        int limit = (kt == qblk) ? q_g : 0x7FFFFFFF;
#pragma unroll
        for (int mt = 0; mt < 4; ++mt) {
            int keyb = k0 + mt * 16 + quad * 4;
            float p0 = exp2f(accs[mt][0]);
            float p1 = exp2f(accs[mt][1]);
            float p2 = exp2f(accs[mt][2]);
            float p3 = exp2f(accs[mt][3]);
            p0 = (keyb + 0 <= limit) ? p0 : 0.f;
            p1 = (keyb + 1 <= limit) ? p1 : 0.f;
            p2 = (keyb + 2 <= limit) ? p2 : 0.f;
            p3 = (keyb + 3 <= limit) ? p3 : 0.f;
            uint2 w2;
            w2.x = bf16pair(p0, p1);
            w2.y = bf16pair(p2, p3);
            *(uint2*)(pp + l16 * 72 + mt * 16 + quad * 4) = w2;   // P[q=l16][key]
        }
        short8 pf0 = *(const short8*)(pp + l16 * 72 + quad * 8);
        short8 pf1 = *(const short8*)(pp + l16 * 72 + 32 + quad * 8);
        // O^T += V^T·P^T: A = V^T rows (d), halves by key
#pragma unroll
        for (int mt = 0; mt < 4; ++mt) {
            short8 vf0 = *(const short8*)(&Vs[0][(mt * 16 + l16) * 32 + quad * 8]);
            short8 vf1 = *(const short8*)(&Vs[1][(mt * 16 + l16) * 32 + quad * 8]);
            acc_o[mt] = __builtin_amdgcn_mfma_f32_16x16x32_bf16(vf0, pf0, acc_o[mt], 0, 0, 0);
            acc_o[mt] = __builtin_amdgcn_mfma_f32_16x16x32_bf16(vf1, pf1, acc_o[mt], 0, 0, 0);
        }
        acc_l = __builtin_amdgcn_mfma_f32_16x16x32_bf16(ones8, pf0, acc_l, 0, 0, 0);
        acc_l = __builtin_amdgcn_mfma_f32_16x16x32_bf16(ones8, pf1, acc_l, 0, 0, 0);
    }
    // epilogue: normalize (row sum from acc_l), osq, transpose via LDS, store
    float inv = 1.f / acc_l[0];
    float part = 0.f;
#pragma unroll
    for (int mt = 0; mt < 4; ++mt) {
        float o0 = acc_o[mt][0] * inv;
        float o1 = acc_o[mt][1] * inv;
        float o2 = acc_o[mt][2] * inv;
        float o3 = acc_o[mt][3] * inv;
        part += o0 * o0 + o1 * o1 + o2 * o2 + o3 * o3;
        uint2 w2;
        w2.x = bf16pair(o0, o1);
        w2.y = bf16pair(o2, o3);
        // O[q = l16][d = mt*16 + quad*4 + ri]
        *(uint2*)(pp + l16 * 72 + mt * 16 + quad * 4) = w2;
    }
    part += __shfl_xor(part, 16, 64);
    part += __shfl_xor(part, 32, 64);
    if (quad == 0) atomicAdd(&osq[(size_t)b * TT + qw + l16], part);
    int rw = lane >> 2, cg = lane & 3;
    uint4 o0 = *(const uint4*)(pp + rw * 72 + cg * 16);
    uint4 o1 = *(const uint4*)(pp + rw * 72 + cg * 16 + 8);
    __hip_bfloat16* orow = out + (size_t)(b * TT + qw + rw) * CC + h * DD + cg * 16;
    *(uint4*)(orow) = o0;
    *(uint4*)(orow + 8) = o1;
}

// ----------------- gemm2: MFMA bf16 GEMM, BK=64, yat epilogue (fp32 out)
template<int TM, int TN, typename OutT>
__global__ __launch_bounds__(256) void yat_gemm_bk64(
    const __hip_bfloat16* __restrict__ A,
    const __hip_bfloat16* __restrict__ Bt,
    const float* __restrict__ xsq, const float* __restrict__ wsq,
    const float* __restrict__ bias, OutT* __restrict__ C,
    int M, int N, int K, float scale) {
    constexpr int MT = TM / 32;
    constexpr int NT = TN / 32;
    constexpr int IA = TM / 64;
    constexpr int IB = TN / 64;
    __shared__ __align__(16) unsigned short As0[TM * 32];
    __shared__ __align__(16) unsigned short As1[TM * 32];
    __shared__ __align__(16) unsigned short Bs0[TN * 32];
    __shared__ __align__(16) unsigned short Bs1[TN * 32];
    int tid = threadIdx.x;
    int wave = tid >> 6, lane = tid & 63, quad = lane >> 4, l16 = lane & 15;
    int wr = wave >> 1, wc = wave & 1;
    int m0 = blockIdx.y * TM, n0 = blockIdx.x * TN;

    f32x4 acc[MT][NT];
#pragma unroll
    for (int mt = 0; mt < MT; ++mt)
#pragma unroll
        for (int nt = 0; nt < NT; ++nt) acc[mt][nt] = f32x4{0.f, 0.f, 0.f, 0.f};

    int srow = lane >> 2, soff = (lane & 3) << 3;
    for (int k0 = 0; k0 < K; k0 += 64) {
        __syncthreads();
#pragma unroll
        for (int i = 0; i < IA; ++i) {
            int rowc = (wave * IA + i) * 16;
            const __hip_bfloat16* ap = A + (size_t)(m0 + rowc + srow) * K + k0 + soff;
            gl_lds16(ap,      As0 + rowc * 32);
            gl_lds16(ap + 32, As1 + rowc * 32);
        }
#pragma unroll
        for (int i = 0; i < IB; ++i) {
            int rowc = (wave * IB + i) * 16;
            const __hip_bfloat16* bp = Bt + (size_t)(n0 + rowc + srow) * K + k0 + soff;
            gl_lds16(bp,      Bs0 + rowc * 32);
            gl_lds16(bp + 32, Bs1 + rowc * 32);
        }
        __syncthreads();
#pragma unroll
        for (int h = 0; h < 2; ++h) {
            const unsigned short* Ah = h ? As1 : As0;
            const unsigned short* Bh = h ? Bs1 : Bs0;
            short8 af[MT], bf[NT];
#pragma unroll
            for (int mt = 0; mt < MT; ++mt)
                af[mt] = *(const short8*)(Ah + (wr * (TM / 2) + mt * 16 + l16) * 32 + quad * 8);
#pragma unroll
            for (int nt = 0; nt < NT; ++nt)
                bf[nt] = *(const short8*)(Bh + (wc * (TN / 2) + nt * 16 + l16) * 32 + quad * 8);
#pragma unroll
            for (int mt = 0; mt < MT; ++mt)
#pragma unroll
                for (int nt = 0; nt < NT; ++nt)
                    acc[mt][nt] = __builtin_amdgcn_mfma_f32_16x16x32_bf16(af[mt], bf[nt], acc[mt][nt], 0, 0, 0);
        }
    }
    int mb = m0 + wr * (TM / 2) + quad * 4;
#pragma unroll
    for (int nt = 0; nt < NT; ++nt) {
        int col = n0 + wc * (TN / 2) + nt * 16 + l16;
        float wq = wsq[col];
        float bs = bias[col];
#pragma unroll
        for (int mt = 0; mt < MT; ++mt) {
#pragma unroll
            for (int r = 0; r < 4; ++r) {
                int row = mb + mt * 16 + r;
                float dot = acc[mt][nt][r];
                float dist = xsq[row] + wq - 2.f * dot + EPS;
                C[(size_t)row * N + col] = (OutT)(dot * dot / dist * scale + bs);
            }
        }
    }
}

// ---------------------------------------------------------------- launcher
extern "C" void kernel_launch(void* const* d_in, const int* in_sizes, int n_in,
                              void* d_out, int out_size, void* d_ws, size_t ws_size,
                              hipStream_t stream) {
    const float* x      = (const float*)d_in[0];
    // d_in[1] = mask (causal tril) — implied analytically, unused
    const float* w_attn = (const float*)d_in[2];
    const float* b_attn = (const float*)d_in[3];
    const float* w_proj = (const float*)d_in[4];
    const float* b_proj = (const float*)d_in[5];
    float* out = (float*)d_out;

    char* ws = (char*)d_ws;
    __hip_bfloat16* xbf  = (__hip_bfloat16*)(ws + 0);         // 8 MB
    __hip_bfloat16* aout = (__hip_bfloat16*)(ws + 8388608);   // 8 MB
    __hip_bfloat16* watT = (__hip_bfloat16*)(ws + 16777216);  // 6 MB
    __hip_bfloat16* wpT  = (__hip_bfloat16*)(ws + 23068672);  // 2 MB
    float*          rope = (float*)(ws + 25165824);           // 512 KB
    float*          xsq  = (float*)(ws + 25690112);           // 16 KB
    float*          osq  = (float*)(ws + 25706496);           // 16 KB
    float*          wsqa = (float*)(ws + 25722880);           // 12 KB
    float*          wsqp = (float*)(ws + 25735168);           // 4 KB
    __hip_bfloat16* Qb   = (__hip_bfloat16*)(ws + 25739264);  // 8 MB [bh][t][d]
    __hip_bfloat16* Kb   = (__hip_bfloat16*)(ws + 34127872);  // 8 MB [bh][t][d]
    __hip_bfloat16* Vb   = (__hip_bfloat16*)(ws + 42516480);  // 8 MB [bh][t][d]
    __hip_bfloat16* Vtb  = (__hip_bfloat16*)(ws + 50905088);  // 8 MB [bh][d][t]

    float scale1 = (float)(sqrt(3072.0) / log1p(3072.0));
    float scale2 = (float)(sqrt(1024.0) / log1p(1024.0));

    rope_rowsq<<<ROWS + 256, 256, 0, stream>>>(x, xsq, xbf, osq, rope, wsqa, wsqp);
    transpose2<<<dim3(48, 16, 2), 256, 0, stream>>>(w_attn, watT, wsqa, w_proj, wpT, wsqp);
    yat_gemm_qkv<<<dim3(N1 / 128, ROWS / 128), 256, 0, stream>>>(
        xbf, watT, xsq, wsqa, b_attn, rope, Qb, Kb, Vb, scale1);
    vtrans<<<dim3(TT / 64, BB * HH), 256, 0, stream>>>((const unsigned short*)Vb, Vtb);
    attn_mfma6<<<1024, 256, 0, stream>>>(Qb, Kb, Vtb, aout, osq);
    yat_gemm_bk64<128, 64, float><<<dim3(CC / 64, ROWS / 128), 256, 0, stream>>>(
        aout, wpT, osq, wsqp, b_proj, out, ROWS, CC, CC, scale2);
}

// Round 10
// 220.576 us; speedup vs baseline: 1.1228x; 1.1187x over previous
//
#include <hip/hip_runtime.h>
#include <hip/hip_bf16.h>
#include <cmath>

// Problem constants
#define BB 2
#define TT 2048
#define CC 1024
#define HH 16
#define DD 64
#define ROWS (BB*TT)          // 4096
#define N1 (3*CC)             // 3072
#define EPS 1e-6f

using short8 = __attribute__((ext_vector_type(8))) short;
using f32x4  = __attribute__((ext_vector_type(4))) float;

__device__ __forceinline__ void gl_lds16(const __hip_bfloat16* g, unsigned short* l) {
    __builtin_amdgcn_global_load_lds(
        (const __attribute__((address_space(1))) unsigned int*)(g),
        (__attribute__((address_space(3))) unsigned int*)(l), 16, 0, 0);
}

__device__ __forceinline__ unsigned int bf16pair(float a, float b) {
    __hip_bfloat16 ha = (__hip_bfloat16)a, hb = (__hip_bfloat16)b;  // RNE
    unsigned short ua = *(unsigned short*)&ha, ub = *(unsigned short*)&hb;
    return (unsigned int)ua | ((unsigned int)ub << 16);
}

__device__ __forceinline__ float bf2f(unsigned short u) {
    unsigned int v = (unsigned int)u << 16;
    return *(float*)&v;
}

// -------- aux1: row sum-of-squares + bf16 cast + rope table + zero inits
__global__ void aux_rowsq(const float* __restrict__ X, float* __restrict__ xsq,
                          __hip_bfloat16* __restrict__ Xb, float* __restrict__ osq,
                          float* __restrict__ rope,
                          float* __restrict__ wsqa, float* __restrict__ wsqp) {
    int blk = blockIdx.x;
    int t = threadIdx.x;
    if (blk >= ROWS) {      // tail blocks: rope table + zero inits
        int idx = (blk - ROWS) * 256 + t;
        if (idx < N1) wsqa[idx] = 0.f;
        if (idx < CC) wsqp[idx] = 0.f;
        if (idx < TT * 32) {
            int tt = idx >> 5, i = idx & 31;
            double freq = pow(10000.0, -(double)i / 32.0);
            float ang = (float)tt * (float)freq;
            rope[idx * 2 + 0] = cosf(ang);
            rope[idx * 2 + 1] = sinf(ang);
        }
        return;
    }
    int row = blk;
    const float* xr = X + (size_t)row * CC;
    __hip_bfloat16* br = Xb + (size_t)row * CC;
    float p = 0.f;
#pragma unroll
    for (int i = 0; i < 4; ++i) {
        float v = xr[t + i * 256];
        p += v * v;
        br[t + i * 256] = (__hip_bfloat16)v;
    }
#pragma unroll
    for (int off = 32; off > 0; off >>= 1) p += __shfl_xor(p, off, 64);
    __shared__ float s4[4];
    if ((t & 63) == 0) s4[t >> 6] = p;
    __syncthreads();
    if (t == 0) { xsq[row] = s4[0] + s4[1] + s4[2] + s4[3]; osq[row] = 0.f; }
}

// ---------- fused transpose of both weights: W (KxN fp32) -> Wt (NxK bf16) + colsq
__global__ void transpose2(const float* __restrict__ Wa, __hip_bfloat16* __restrict__ WaT,
                           float* __restrict__ wsqa,
                           const float* __restrict__ Wp, __hip_bfloat16* __restrict__ WpT,
                           float* __restrict__ wsqp) {
    const float* W; __hip_bfloat16* Wt; float* wsq; int N;
    if (blockIdx.z == 0) { W = Wa; Wt = WaT; wsq = wsqa; N = N1; }
    else { if (blockIdx.x >= 16) return; W = Wp; Wt = WpT; wsq = wsqp; N = CC; }
    const int K = CC;
    __shared__ unsigned short tile[64][65];
    int n0 = blockIdx.x * 64, k0 = blockIdx.y * 64;
    int c = threadIdx.x & 63, rg = threadIdx.x >> 6;
    float part = 0.f;
#pragma unroll
    for (int rr = 0; rr < 16; ++rr) {
        int r = rg + rr * 4;
        float f = W[(size_t)(k0 + r) * N + n0 + c];
        __hip_bfloat16 h = (__hip_bfloat16)f;
        tile[r][c] = *(unsigned short*)&h;
        part += f * f;
    }
    atomicAdd(&wsq[n0 + c], part);
    __syncthreads();
#pragma unroll
    for (int rr = 0; rr < 16; ++rr) {
        int r = rg + rr * 4;
        unsigned short u = tile[c][r];
        Wt[(size_t)(n0 + r) * K + k0 + c] = *(__hip_bfloat16*)&u;
    }
}

// --------- gemm1: x @ w_attn, yat epilogue, scatter to Qb/Kb/Vb [bh][t][d]
// 128x128 tile, BK=64. NO rope (done by consumers).
__global__ __launch_bounds__(256) void yat_gemm_qkv2(
    const __hip_bfloat16* __restrict__ A,
    const __hip_bfloat16* __restrict__ Bt,
    const float* __restrict__ xsq, const float* __restrict__ wsq,
    const float* __restrict__ bias,
    __hip_bfloat16* __restrict__ Qb, __hip_bfloat16* __restrict__ Kb,
    __hip_bfloat16* __restrict__ Vb, float scale) {
    const int K = CC;
    __shared__ __align__(16) unsigned short As0[128 * 32], As1[128 * 32];
    __shared__ __align__(16) unsigned short Bs0[128 * 32], Bs1[128 * 32];
    int tid = threadIdx.x;
    int wave = tid >> 6, lane = tid & 63, quad = lane >> 4, l16 = lane & 15;
    int wr = wave >> 1, wc = wave & 1;
    int m0 = blockIdx.y * 128, n0 = blockIdx.x * 128;

    f32x4 acc[4][4];
#pragma unroll
    for (int mt = 0; mt < 4; ++mt)
#pragma unroll
        for (int nt = 0; nt < 4; ++nt) acc[mt][nt] = f32x4{0.f, 0.f, 0.f, 0.f};

    int srow = lane >> 2, soff = (lane & 3) << 3;
    for (int k0 = 0; k0 < K; k0 += 64) {
        __syncthreads();
#pragma unroll
        for (int i = 0; i < 2; ++i) {
            int rowc = (wave * 2 + i) * 16;
            const __hip_bfloat16* ap = A + (size_t)(m0 + rowc + srow) * K + k0 + soff;
            gl_lds16(ap,      As0 + rowc * 32);
            gl_lds16(ap + 32, As1 + rowc * 32);
            const __hip_bfloat16* bp = Bt + (size_t)(n0 + rowc + srow) * K + k0 + soff;
            gl_lds16(bp,      Bs0 + rowc * 32);
            gl_lds16(bp + 32, Bs1 + rowc * 32);
        }
        __syncthreads();
#pragma unroll
        for (int h = 0; h < 2; ++h) {
            const unsigned short* Ah = h ? As1 : As0;
            const unsigned short* Bh = h ? Bs1 : Bs0;
            short8 af[4], bf[4];
#pragma unroll
            for (int mt = 0; mt < 4; ++mt)
                af[mt] = *(const short8*)(Ah + (wr * 64 + mt * 16 + l16) * 32 + quad * 8);
#pragma unroll
            for (int nt = 0; nt < 4; ++nt)
                bf[nt] = *(const short8*)(Bh + (wc * 64 + nt * 16 + l16) * 32 + quad * 8);
#pragma unroll
            for (int mt = 0; mt < 4; ++mt)
#pragma unroll
                for (int nt = 0; nt < 4; ++nt)
                    acc[mt][nt] = __builtin_amdgcn_mfma_f32_16x16x32_bf16(af[mt], bf[nt], acc[mt][nt], 0, 0, 0);
        }
    }
    int mb = m0 + wr * 64 + quad * 4;
#pragma unroll
    for (int nt = 0; nt < 4; ++nt) {
        int col = n0 + wc * 64 + nt * 16 + l16;
        float wq = wsq[col], bs = bias[col];
        int sec = col >> 10, cc2 = col & 1023;
        int h = cc2 >> 6, d = cc2 & 63;
        __hip_bfloat16* dst = (sec == 0) ? Qb : ((sec == 1) ? Kb : Vb);
#pragma unroll
        for (int mt = 0; mt < 4; ++mt) {
#pragma unroll
            for (int r = 0; r < 4; ++r) {
                int row = mb + mt * 16 + r;
                float dot = acc[mt][nt][r];
                float dist = xsq[row] + wq - 2.f * dot + EPS;
                float y = dot * dot / dist * scale + bs;
                int t = row & (TT - 1), bI = row >> 11;
                dst[(((size_t)bI * HH + h) * TT + t) * DD + d] = (__hip_bfloat16)y;
            }
        }
    }
}

// ------------- rope K in place + transpose V: Vb [bh][t][d] -> Vtb [bh][d][t]
__global__ __launch_bounds__(256) void ropek_vtrans(
    unsigned short* __restrict__ Kb, const unsigned short* __restrict__ Vb,
    __hip_bfloat16* __restrict__ Vtb, const float* __restrict__ rope) {
    int bh = blockIdx.y, t0 = blockIdx.x * 64, tid = threadIdx.x;
    __shared__ unsigned short vt[64][72];
    int r = tid >> 2, g = tid & 3;
    const unsigned short* src = Vb + ((size_t)bh * TT + t0 + r) * DD + g * 16;
    *(uint4*)&vt[r][g * 16]     = *(const uint4*)src;
    *(uint4*)&vt[r][g * 16 + 8] = *(const uint4*)(src + 8);
    // K rope in place (each element owned by exactly one thread)
    {
        int t = t0 + r;
        unsigned short* kp = Kb + ((size_t)bh * TT + t) * DD + g * 16;
        union U8 { uint4 v; unsigned short s[8]; } k0v, k1v, o0, o1;
        k0v.v = *(const uint4*)kp;
        k1v.v = *(const uint4*)(kp + 8);
        const float* rp = rope + (size_t)t * 64 + g * 16;
#pragma unroll
        for (int u = 0; u < 8; ++u) {
            float c = rp[2 * u], sn = rp[2 * u + 1];
            unsigned short ev = (u < 4) ? k0v.s[2 * u]     : k1v.s[2 * u - 8];
            unsigned short ov = (u < 4) ? k0v.s[2 * u + 1] : k1v.s[2 * u - 7];
            float f0 = bf2f(ev), f1 = bf2f(ov);
            unsigned int pr = bf16pair(f0 * c - f1 * sn, f1 * c + f0 * sn);
            if (u < 4) ((unsigned int*)&o0)[u] = pr;
            else       ((unsigned int*)&o1)[u - 4] = pr;
        }
        *(uint4*)kp = o0.v;
        *(uint4*)(kp + 8) = o1.v;
    }
    __syncthreads();
    union U8b { uint4 v; unsigned short s[8]; };
#pragma unroll
    for (int p = 0; p < 2; ++p) {
        int d = (tid >> 3) + p * 32, tl = (tid & 7) * 8;
        U8b w;
#pragma unroll
        for (int j = 0; j < 8; ++j) w.s[j] = vt[tl + j][d];
        *(uint4*)(Vtb + ((size_t)bh * DD + d) * TT + t0 + tl) = w.v;
    }
}

// ------------------------ LDS-staged MFMA flash attention, double-buffered
// Grid 768, 3 blocks/CU exact. Light blocks (s<8) process qblk pair (v,15-v)
// = 17 tiles; heavy blocks 1 qblk (17+a / 32-a tiles). Under round-robin
// intra-XCD dispatch each CU gets {17, 17+a, 32-a} = 66 tiles.
// One barrier per tile: stage(buf0); loop{ barrier; prefetch(buf^1); compute }.
// Q roped in-register at load (pairs adjacent in k-dim within lane).
__global__ __launch_bounds__(256, 3) void attn_mfma8(
    const __hip_bfloat16* __restrict__ Qb, const __hip_bfloat16* __restrict__ Kb,
    const __hip_bfloat16* __restrict__ Vtb, const float* __restrict__ rope,
    __hip_bfloat16* __restrict__ out, float* __restrict__ osq) {
    const float QSC = 0.125f * 1.44269504f;
    int i = blockIdx.x;
    int xcd = i & 7, jj = (i >> 3) & 3, s = i >> 5;   // s = 0..23
    int bh = xcd + 8 * jj;
    int b = bh >> 4, h = bh & 15;
    int tid = threadIdx.x;
    int wave = tid >> 6, lane = tid & 63, quad = lane >> 4, l16 = lane & 15;

    __shared__ __align__(16) unsigned short Ks[2][2][64 * 32];
    __shared__ __align__(16) unsigned short Vs[2][2][64 * 32];
    __shared__ __align__(16) unsigned short Ps[4][16 * 72];
    unsigned short* pp = &Ps[wave][0];

    const __hip_bfloat16* Qbase = Qb + (size_t)bh * TT * DD;
    const __hip_bfloat16* Kbase = Kb + (size_t)bh * TT * DD;
    const __hip_bfloat16* Vbase = Vtb + (size_t)bh * DD * TT;

    int srow = lane >> 2, soff = (lane & 3) * 8;
    short8 ones8;
#pragma unroll
    for (int u = 0; u < 8; ++u) ones8[u] = (short)0x3F80;   // bf16 1.0

    int u0, u1, nunits;
    if (s < 8)       { u0 = s;      u1 = 15 - s; nunits = 2; }
    else if (s < 16) { u0 = s + 8;  u1 = 0;      nunits = 1; }
    else             { u0 = 47 - s; u1 = 0;      nunits = 1; }

    for (int un = 0; un < nunits; ++un) {
        int qblk = un ? u1 : u0;
        int qw = qblk * 64 + wave * 16;
        // ---- load Q raw + rope in registers (scaled by QSC)
        short8 qf0, qf1;
        {
            int t = qw + l16;
            const unsigned short* qr = (const unsigned short*)(Qbase + (size_t)t * DD) + quad * 8;
            union S8 { short8 v; unsigned short s[8]; } r0, r1, o0v, o1v;
            r0.v = *(const short8*)qr;
            r1.v = *(const short8*)(qr + 32);
            const float* rpa = rope + (size_t)t * 64 + quad * 8;
            const float* rpb = rpa + 32;
#pragma unroll
            for (int u = 0; u < 4; ++u) {
                float c = rpa[2 * u] * QSC, sn = rpa[2 * u + 1] * QSC;
                float e = bf2f(r0.s[2 * u]), o = bf2f(r0.s[2 * u + 1]);
                ((unsigned int*)&o0v)[u] = bf16pair(e * c - o * sn, o * c + e * sn);
                float c2 = rpb[2 * u] * QSC, sn2 = rpb[2 * u + 1] * QSC;
                float e2 = bf2f(r1.s[2 * u]), o2 = bf2f(r1.s[2 * u + 1]);
                ((unsigned int*)&o1v)[u] = bf16pair(e2 * c2 - o2 * sn2, o2 * c2 + e2 * sn2);
            }
            qf0 = o0v.v;
            qf1 = o1v.v;
        }
        f32x4 acc_o[4];
#pragma unroll
        for (int mt = 0; mt < 4; ++mt) acc_o[mt] = f32x4{0.f, 0.f, 0.f, 0.f};
        f32x4 acc_l = {0.f, 0.f, 0.f, 0.f};
        int q_g = qw + l16;

        __syncthreads();           // protect buf0 from previous unit's readers
        // stage tile 0 into buffer 0
        gl_lds16(Kbase + (size_t)(wave * 16 + srow) * DD + soff,      &Ks[0][0][wave * 512]);
        gl_lds16(Kbase + (size_t)(wave * 16 + srow) * DD + 32 + soff, &Ks[0][1][wave * 512]);
        gl_lds16(Vbase + (size_t)(wave * 16 + srow) * TT + soff,      &Vs[0][0][wave * 512]);
        gl_lds16(Vbase + (size_t)(wave * 16 + srow) * TT + 32 + soff, &Vs[0][1][wave * 512]);

        for (int kt = 0; kt <= qblk; ++kt) {
            int cur = kt & 1;
            int k0 = kt * 64;
            __syncthreads();       // drains staging of buf cur; compute of kt-1 done
            if (kt < qblk) {       // prefetch next tile into other buffer
                int nb = cur ^ 1, kn = k0 + 64;
                gl_lds16(Kbase + (size_t)(kn + wave * 16 + srow) * DD + soff,      &Ks[nb][0][wave * 512]);
                gl_lds16(Kbase + (size_t)(kn + wave * 16 + srow) * DD + 32 + soff, &Ks[nb][1][wave * 512]);
                gl_lds16(Vbase + (size_t)(wave * 16 + srow) * TT + kn + soff,      &Vs[nb][0][wave * 512]);
                gl_lds16(Vbase + (size_t)(wave * 16 + srow) * TT + kn + 32 + soff, &Vs[nb][1][wave * 512]);
            }
            // S^T = K·Q^T
            f32x4 accs[4];
#pragma unroll
            for (int mt = 0; mt < 4; ++mt) {
                short8 kf0 = *(const short8*)(&Ks[cur][0][(mt * 16 + l16) * 32 + quad * 8]);
                short8 kf1 = *(const short8*)(&Ks[cur][1][(mt * 16 + l16) * 32 + quad * 8]);
                f32x4 z = {0.f, 0.f, 0.f, 0.f};
                z = __builtin_amdgcn_mfma_f32_16x16x32_bf16(kf0, qf0, z, 0, 0, 0);
                accs[mt] = __builtin_amdgcn_mfma_f32_16x16x32_bf16(kf1, qf1, z, 0, 0, 0);
            }
            int limit = (kt == qblk) ? q_g : 0x7FFFFFFF;
#pragma unroll
            for (int mt = 0; mt < 4; ++mt) {
                int keyb = k0 + mt * 16 + quad * 4;
                float p0 = exp2f(accs[mt][0]);
                float p1 = exp2f(accs[mt][1]);
                float p2 = exp2f(accs[mt][2]);
                float p3 = exp2f(accs[mt][3]);
                p0 = (keyb + 0 <= limit) ? p0 : 0.f;
                p1 = (keyb + 1 <= limit) ? p1 : 0.f;
                p2 = (keyb + 2 <= limit) ? p2 : 0.f;
                p3 = (keyb + 3 <= limit) ? p3 : 0.f;
                uint2 w2;
                w2.x = bf16pair(p0, p1);
                w2.y = bf16pair(p2, p3);
                *(uint2*)(pp + l16 * 72 + mt * 16 + quad * 4) = w2;   // P[q=l16][key]
            }
            short8 pf0 = *(const short8*)(pp + l16 * 72 + quad * 8);
            short8 pf1 = *(const short8*)(pp + l16 * 72 + 32 + quad * 8);
            // O^T += V^T·P^T
#pragma unroll
            for (int mt = 0; mt < 4; ++mt) {
                short8 vf0 = *(const short8*)(&Vs[cur][0][(mt * 16 + l16) * 32 + quad * 8]);
                short8 vf1 = *(const short8*)(&Vs[cur][1][(mt * 16 + l16) * 32 + quad * 8]);
                acc_o[mt] = __builtin_amdgcn_mfma_f32_16x16x32_bf16(vf0, pf0, acc_o[mt], 0, 0, 0);
                acc_o[mt] = __builtin_amdgcn_mfma_f32_16x16x32_bf16(vf1, pf1, acc_o[mt], 0, 0, 0);
            }
            acc_l = __builtin_amdgcn_mfma_f32_16x16x32_bf16(ones8, pf0, acc_l, 0, 0, 0);
            acc_l = __builtin_amdgcn_mfma_f32_16x16x32_bf16(ones8, pf1, acc_l, 0, 0, 0);
        }
        // epilogue: normalize, osq, transpose via wave-private strip, store
        float inv = 1.f / acc_l[0];
        float part = 0.f;
#pragma unroll
        for (int mt = 0; mt < 4; ++mt) {
            float o0 = acc_o[mt][0] * inv;
            float o1 = acc_o[mt][1] * inv;
            float o2 = acc_o[mt][2] * inv;
            float o3 = acc_o[mt][3] * inv;
            part += o0 * o0 + o1 * o1 + o2 * o2 + o3 * o3;
            uint2 w2;
            w2.x = bf16pair(o0, o1);
            w2.y = bf16pair(o2, o3);
            *(uint2*)(pp + l16 * 72 + mt * 16 + quad * 4) = w2;   // O[q=l16][d]
        }
        part += __shfl_xor(part, 16, 64);
        part += __shfl_xor(part, 32, 64);
        if (quad == 0) atomicAdd(&osq[(size_t)b * TT + qw + l16], part);
        int rw = lane >> 2, cg = lane & 3;
        uint4 o0 = *(const uint4*)(pp + rw * 72 + cg * 16);
        uint4 o1 = *(const uint4*)(pp + rw * 72 + cg * 16 + 8);
        __hip_bfloat16* orow = out + (size_t)(b * TT + qw + rw) * CC + h * DD + cg * 16;
        *(uint4*)(orow) = o0;
        *(uint4*)(orow + 8) = o1;
    }
}

// ----------------- gemm2: MFMA bf16 GEMM, BK=64, yat epilogue (generic)
template<int TM, int TN, typename OutT>
__global__ __launch_bounds__(256) void yat_gemm_bk64(
    const __hip_bfloat16* __restrict__ A,
    const __hip_bfloat16* __restrict__ Bt,
    const float* __restrict__ xsq, const float* __restrict__ wsq,
    const float* __restrict__ bias, OutT* __restrict__ C,
    int M, int N, int K, float scale) {
    constexpr int MT = TM / 32;
    constexpr int NT = TN / 32;
    constexpr int IA = TM / 64;
    constexpr int IB = TN / 64;
    __shared__ __align__(16) unsigned short As0[TM * 32];
    __shared__ __align__(16) unsigned short As1[TM * 32];
    __shared__ __align__(16) unsigned short Bs0[TN * 32];
    __shared__ __align__(16) unsigned short Bs1[TN * 32];
    int tid = threadIdx.x;
    int wave = tid >> 6, lane = tid & 63, quad = lane >> 4, l16 = lane & 15;
    int wr = wave >> 1, wc = wave & 1;
    int m0 = blockIdx.y * TM, n0 = blockIdx.x * TN;

    f32x4 acc[MT][NT];
#pragma unroll
    for (int mt = 0; mt < MT; ++mt)
#pragma unroll
        for (int nt = 0; nt < NT; ++nt) acc[mt][nt] = f32x4{0.f, 0.f, 0.f, 0.f};

    int srow = lane >> 2, soff = (lane & 3) << 3;
    for (int k0 = 0; k0 < K; k0 += 64) {
        __syncthreads();
#pragma unroll
        for (int i = 0; i < IA; ++i) {
            int rowc = (wave * IA + i) * 16;
            const __hip_bfloat16* ap = A + (size_t)(m0 + rowc + srow) * K + k0 + soff;
            gl_lds16(ap,      As0 + rowc * 32);
            gl_lds16(ap + 32, As1 + rowc * 32);
        }
#pragma unroll
        for (int i = 0; i < IB; ++i) {
            int rowc = (wave * IB + i) * 16;
            const __hip_bfloat16* bp = Bt + (size_t)(n0 + rowc + srow) * K + k0 + soff;
            gl_lds16(bp,      Bs0 + rowc * 32);
            gl_lds16(bp + 32, Bs1 + rowc * 32);
        }
        __syncthreads();
#pragma unroll
        for (int h = 0; h < 2; ++h) {
            const unsigned short* Ah = h ? As1 : As0;
            const unsigned short* Bh = h ? Bs1 : Bs0;
            short8 af[MT], bf[NT];
#pragma unroll
            for (int mt = 0; mt < MT; ++mt)
                af[mt] = *(const short8*)(Ah + (wr * (TM / 2) + mt * 16 + l16) * 32 + quad * 8);
#pragma unroll
            for (int nt = 0; nt < NT; ++nt)
                bf[nt] = *(const short8*)(Bh + (wc * (TN / 2) + nt * 16 + l16) * 32 + quad * 8);
#pragma unroll
            for (int mt = 0; mt < MT; ++mt)
#pragma unroll
                for (int nt = 0; nt < NT; ++nt)
                    acc[mt][nt] = __builtin_amdgcn_mfma_f32_16x16x32_bf16(af[mt], bf[nt], acc[mt][nt], 0, 0, 0);
        }
    }
    int mb = m0 + wr * (TM / 2) + quad * 4;
#pragma unroll
    for (int nt = 0; nt < NT; ++nt) {
        int col = n0 + wc * (TN / 2) + nt * 16 + l16;
        float wq = wsq[col];
        float bs = bias[col];
#pragma unroll
        for (int mt = 0; mt < MT; ++mt) {
#pragma unroll
            for (int r = 0; r < 4; ++r) {
                int row = mb + mt * 16 + r;
                float dot = acc[mt][nt][r];
                float dist = xsq[row] + wq - 2.f * dot + EPS;
                C[(size_t)row * N + col] = (OutT)(dot * dot / dist * scale + bs);
            }
        }
    }
}

// ---------------------------------------------------------------- launcher
extern "C" void kernel_launch(void* const* d_in, const int* in_sizes, int n_in,
                              void* d_out, int out_size, void* d_ws, size_t ws_size,
                              hipStream_t stream) {
    const float* x      = (const float*)d_in[0];
    // d_in[1] = mask (causal tril) — implied analytically, unused
    const float* w_attn = (const float*)d_in[2];
    const float* b_attn = (const float*)d_in[3];
    const float* w_proj = (const float*)d_in[4];
    const float* b_proj = (const float*)d_in[5];
    float* out = (float*)d_out;

    char* ws = (char*)d_ws;
    __hip_bfloat16* xbf  = (__hip_bfloat16*)(ws + 0);         // 8 MB
    __hip_bfloat16* aout = (__hip_bfloat16*)(ws + 8388608);   // 8 MB
    __hip_bfloat16* watT = (__hip_bfloat16*)(ws + 16777216);  // 6 MB
    __hip_bfloat16* wpT  = (__hip_bfloat16*)(ws + 23068672);  // 2 MB
    float*          rope = (float*)(ws + 25165824);           // 512 KB
    float*          xsq  = (float*)(ws + 25690112);           // 16 KB
    float*          osq  = (float*)(ws + 25706496);           // 16 KB
    float*          wsqa = (float*)(ws + 25722880);           // 12 KB
    float*          wsqp = (float*)(ws + 25735168);           // 4 KB
    __hip_bfloat16* Qb   = (__hip_bfloat16*)(ws + 25739264);  // 8 MB [bh][t][d]
    __hip_bfloat16* Kb   = (__hip_bfloat16*)(ws + 34127872);  // 8 MB [bh][t][d]
    __hip_bfloat16* Vb   = (__hip_bfloat16*)(ws + 42516480);  // 8 MB [bh][t][d]
    __hip_bfloat16* Vtb  = (__hip_bfloat16*)(ws + 50905088);  // 8 MB [bh][d][t]

    float scale1 = (float)(sqrt(3072.0) / log1p(3072.0));
    float scale2 = (float)(sqrt(1024.0) / log1p(1024.0));

    aux_rowsq<<<ROWS + 256, 256, 0, stream>>>(x, xsq, xbf, osq, rope, wsqa, wsqp);
    transpose2<<<dim3(48, 16, 2), 256, 0, stream>>>(w_attn, watT, wsqa, w_proj, wpT, wsqp);
    yat_gemm_qkv2<<<dim3(N1 / 128, ROWS / 128), 256, 0, stream>>>(
        xbf, watT, xsq, wsqa, b_attn, Qb, Kb, Vb, scale1);
    ropek_vtrans<<<dim3(TT / 64, BB * HH), 256, 0, stream>>>(
        (unsigned short*)Kb, (const unsigned short*)Vb, Vtb, rope);
    attn_mfma8<<<768, 256, 0, stream>>>(Qb, Kb, Vtb, rope, aout, osq);
    yat_gemm_bk64<64, 64, float><<<dim3(CC / 64, ROWS / 64), 256, 0, stream>>>(
        aout, wpT, osq, wsqp, b_proj, out, ROWS, CC, CC, scale2);
}